// Round 12
// baseline (2440.409 us; speedup 1.0000x reference)
//
#include <hip/hip_runtime.h>

typedef _Float16 f16;
typedef _Float16 f16x4v __attribute__((ext_vector_type(4)));
typedef _Float16 f16x8  __attribute__((ext_vector_type(8)));
typedef float    f32x4  __attribute__((ext_vector_type(4)));
typedef unsigned long long u64;
typedef unsigned int u32;

#define NB 32
#define NT 512
#define NF 512
#define NH 512
#define NG 2048   // 4*NH gate columns

// workspace layout (bytes)
static const size_t XH_OFF   = 0;
static const size_t XH_BYTES = (size_t)NB*NT*NF*2;        // 16 MiB fp16 x
static const size_t WT_OFF   = XH_OFF + XH_BYTES;
static const size_t WT_BYTES = (size_t)2*NG*1024*2;       //  8 MiB Wt[dir][col][k] fp16
static const size_t GX_OFF   = WT_OFF + WT_BYTES;
static const size_t GX_BYTES = (size_t)2*NT*65536*2;      // 128 MiB gxp[dir*NT+slot][rank][grp][thr256][16]
static const size_t HB_OFF   = GX_OFF + GX_BYTES;
static const size_t HB_BYTES = (size_t)2*2*2*16*128*8;    // 128 KiB hbuf[grp][par][dir][b16][ko128] u64

__device__ __forceinline__ float sigf(float x){ return 1.0f/(1.0f+__expf(-x)); }
__device__ __forceinline__ float tanh_f(float x){ return 1.0f - 2.0f/(__expf(2.0f*x)+1.0f); }

// raw barrier: LDS-ordering only; VMEM (stores/prefetches) stay in flight.
__device__ __forceinline__ void barrier_lgkm() {
  asm volatile("s_waitcnt lgkmcnt(0)" ::: "memory");
  __builtin_amdgcn_sched_barrier(0);
  __builtin_amdgcn_s_barrier();
  __builtin_amdgcn_sched_barrier(0);
  asm volatile("" ::: "memory");
}

__global__ void k_zero(float4* o, size_t no, uint4* z, size_t nz) {
  size_t i = (size_t)blockIdx.x*blockDim.x + threadIdx.x;
  size_t st = (size_t)gridDim.x*blockDim.x;
  float4 fz = make_float4(0.f,0.f,0.f,0.f);
  uint4  uz = make_uint4(0u,0u,0u,0u);
  for (size_t j=i; j<no; j+=st) o[j]=fz;
  for (size_t j=i; j<nz; j+=st) z[j]=uz;
}

__global__ void k_cvt(const float* __restrict__ x, f16* __restrict__ xh) {
  size_t i = ((size_t)blockIdx.x*blockDim.x + threadIdx.x)*4;
  float4 v = *(const float4*)(x+i);
  f16x4v h; h[0]=(f16)v.x; h[1]=(f16)v.y; h[2]=(f16)v.z; h[3]=(f16)v.w;
  *(f16x4v*)(xh+i) = h;
}

// W [1024][2048] f32 -> Wt[dir][col 2048][k 1024] fp16 (tiled transpose)
__global__ void k_tw(const float* __restrict__ Wfw, const float* __restrict__ Wbw,
                     f16* __restrict__ Wt) {
  __shared__ f16 tile[32][33];
  int b = blockIdx.x;
  int dir = b >> 11; int rem = b & 2047;
  int kt = rem >> 6, ct = rem & 63;
  const float* W = dir ? Wbw : Wfw;
  int tx = threadIdx.x & 31, ty0 = threadIdx.x >> 5;
  int k0 = kt*32, c0 = ct*32;
  for (int yy=ty0; yy<32; yy+=8)
    tile[yy][tx] = (f16)W[(size_t)(k0+yy)*2048 + c0 + tx];
  __syncthreads();
  f16* Wd = Wt + (size_t)dir*2048*1024;
  for (int yy=ty0; yy<32; yy+=8)
    Wd[(size_t)(c0+yy)*1024 + k0 + tx] = tile[tx][yy];
}

// gxp = x@Wx + bias, consumer layout:
// [dir*NT+slot][rank8][grp2][thread256 = ct*64+q*16+cc][gate4][rr4] f16
// bw time reversal folded into slot (bijection per batch).
__global__ __launch_bounds__(256) void k_gx(const f16* __restrict__ xh,
    const f16* __restrict__ Wt, const float* __restrict__ bfw,
    const float* __restrict__ bbw, const int* __restrict__ seqlen,
    f16* __restrict__ gxp)
{
  __shared__ f16 As[128*32];
  __shared__ f16 Bs[128*32];
  int bm0 = blockIdx.x * 128;
  int bn0 = blockIdx.y * 128;
  int dir = blockIdx.z;
  const f16* Wd = Wt + (size_t)dir*NG*1024;
  const float* bias = dir ? bbw : bfw;

  int tid = threadIdx.x;
  int w = tid>>6, lane = tid&63;
  int cc = lane&15, q = lane>>4;
  int wm = w>>1, wn = w&1;

  f32x4 acc[4][4];
#pragma unroll
  for (int i=0;i<4;++i)
#pragma unroll
    for (int j=0;j<4;++j) acc[i][j] = (f32x4){0.f,0.f,0.f,0.f};

  for (int kt=0; kt<16; ++kt) {
    int k0 = kt*32;
#pragma unroll
    for (int c=0;c<2;++c) {
      int ch = w*2 + c;
      int row = ch*16 + (lane>>2);
      int cph = (lane&3)*16;
      int clg = cph ^ (((row>>1)&3)<<4);
      const f16* ga = xh + (size_t)(bm0+row)*NF   + k0 + (clg>>1);
      const f16* gb = Wd + (size_t)(bn0+row)*1024 + k0 + (clg>>1);
      __builtin_amdgcn_global_load_lds(
          (const __attribute__((address_space(1))) u32*)ga,
          (__attribute__((address_space(3))) u32*)(As + ch*512), 16, 0, 0);
      __builtin_amdgcn_global_load_lds(
          (const __attribute__((address_space(1))) u32*)gb,
          (__attribute__((address_space(3))) u32*)(Bs + ch*512), 16, 0, 0);
    }
    __syncthreads();

    f16x8 av[4], bv[4];
#pragma unroll
    for (int mi=0;mi<4;++mi) {
      int r = wm*64 + mi*16 + cc;
      int sw = ((r>>1)&3)<<4;
      u64 lo = *(const u64*)&As[r*32 + ((((q*8)   ) ^ sw)>>1)];
      u64 hi = *(const u64*)&As[r*32 + ((((q*8)+32) ^ sw)>>1)];
      f16x4v l4 = __builtin_bit_cast(f16x4v, lo);
      f16x4v h4 = __builtin_bit_cast(f16x4v, hi);
      f16x8 a; a[0]=l4[0];a[1]=l4[1];a[2]=l4[2];a[3]=l4[3];
      a[4]=h4[0];a[5]=h4[1];a[6]=h4[2];a[7]=h4[3];
      av[mi]=a;
    }
#pragma unroll
    for (int ni=0;ni<4;++ni) {
      int r = wn*64 + ni*16 + cc;
      int sw = ((r>>1)&3)<<4;
      u64 lo = *(const u64*)&Bs[r*32 + ((((q*8)   ) ^ sw)>>1)];
      u64 hi = *(const u64*)&Bs[r*32 + ((((q*8)+32) ^ sw)>>1)];
      f16x4v l4 = __builtin_bit_cast(f16x4v, lo);
      f16x4v h4 = __builtin_bit_cast(f16x4v, hi);
      f16x8 a; a[0]=l4[0];a[1]=l4[1];a[2]=l4[2];a[3]=l4[3];
      a[4]=h4[0];a[5]=h4[1];a[6]=h4[2];a[7]=h4[3];
      bv[ni]=a;
    }
#pragma unroll
    for (int mi=0;mi<4;++mi)
#pragma unroll
      for (int ni=0;ni<4;++ni)
        acc[mi][ni] = __builtin_amdgcn_mfma_f32_16x16x32_f16(av[mi], bv[ni], acc[mi][ni], 0,0,0);
    __syncthreads();
  }

  // epilogue: scatter into consumer layout
  int b = bm0 >> 9;             // this block's single batch
  int L = seqlen[b];
  int grp = b >> 4, bl = b & 15;
  int q_c = bl >> 2, rr_c = bl & 3;
#pragma unroll
  for (int ni=0;ni<4;++ni) {
    int col = bn0 + wn*64 + ni*16 + cc;
    int gate = col >> 9, n = col & 511;
    int rk = n >> 6, c_l = n & 63;
    int ct_c = c_l >> 4, cc_c = c_l & 15;
    float bvl = bias[col];
    size_t coff = (size_t)((((rk*2 + grp)*256 + ct_c*64 + q_c*16 + cc_c))*16 + gate*4 + rr_c);
#pragma unroll
    for (int mi=0;mi<4;++mi)
#pragma unroll
      for (int rr=0;rr<4;++rr) {
        int t = (bm0&511) + wm*64 + mi*16 + q*4 + rr;
        int slot = dir ? ((t < L) ? (L-1-t) : t) : t;
        gxp[(size_t)(dir*NT + slot)*65536 + coff] = (f16)(acc[mi][ni][rr] + bvl);
      }
  }
}

// Persistent recurrence: 32 blocks (dir x rank x grp), 256 threads (4 waves).
// Wave ct owns cols [rank*64 + ct*16, +16) x ALL 4 gates; W resident (VGPR+AGPR).
// Tag-in-data ping-pong (proven protocol). KEY R12 change: VMEM issue order is
//   publish (earliest visibility) -> candidate+gx prefetch -> out stores LAST
// so the consumer's vmcnt wait on candidates never drains scattered HBM
// out-stores, and the publish isn't queued behind them (R4/R11 lesson).
__global__ __launch_bounds__(256, 1)
void k_rnn(const f16* __restrict__ gxp, const f16* __restrict__ Wt,
           u64* hbuf, const int* __restrict__ seqlen, float* __restrict__ out)
{
  __shared__ u64 hstage[2][16*129];
  int bid = blockIdx.x;
  int dir = bid >> 4, rank = (bid >> 1) & 7, grp = bid & 1;
  int tid = threadIdx.x;
  int ct = tid >> 6, lane = tid & 63, cc = lane & 15, q = lane >> 4;
  int ncol0 = rank*64 + ct*16;

  // Persistent W_h: col = g*NH + ncol0 + cc; k = 512 + kk*32 + q*4 (+16)
  f16x8 Wf[16][4];
  {
    const f16* Wd = Wt + (size_t)dir*NG*1024;
#pragma unroll
    for (int kk=0;kk<16;++kk)
#pragma unroll
      for (int g=0;g<4;++g) {
        const f16* pp = Wd + (size_t)(g*NH + ncol0 + cc)*1024 + 512 + kk*32 + q*4;
        f16x4v lo = *(const f16x4v*)pp;
        f16x4v hi = *(const f16x4v*)(pp+16);
        f16x8 a; a[0]=lo[0];a[1]=lo[1];a[2]=lo[2];a[3]=lo[3];
        a[4]=hi[0];a[5]=hi[1];a[6]=hi[2];a[7]=hi[3];
        Wf[kk][g] = a;
      }
  }
  // pin: values become asm-opaque -> cannot be rematerialized (re-loaded) in-loop
#pragma unroll
  for (int kk=0;kk<16;++kk)
#pragma unroll
    for (int g=0;g<4;++g)
      asm volatile("" : "+v"(Wf[kk][g]));

  int Lr[4];
#pragma unroll
  for (int rr=0;rr<4;++rr) Lr[rr] = seqlen[grp*16 + q*4 + rr];

  float cst[4] = {0.f,0.f,0.f,0.f}, hst[4] = {0.f,0.f,0.f,0.f};

  int cb_b = tid >> 4;      // candidate batch 0..15
  int cb_k = tid & 15;      // candidate ko base
  u64 cu[8] = {0,0,0,0,0,0,0,0};

  uint4 gxa = *(const uint4*)(gxp + (size_t)(dir*NT + 0)*65536
                              + ((size_t)(rank*2 + grp)*256 + tid)*16);
  uint4 gxb = *(const uint4*)(gxp + (size_t)(dir*NT + 0)*65536
                              + ((size_t)(rank*2 + grp)*256 + tid)*16 + 8);

  for (int s = 0; s < NT; ++s) {
    int pr = s & 1;
    u64 tgr = (u64)(((s+1)>>1) & 1);
    u64 tgw = (u64)(((s+2)>>1) & 1);

    f32x4 acc[4];
#pragma unroll
    for (int g=0;g<4;++g) acc[g] = (f32x4){0.f,0.f,0.f,0.f};

    if (s > 0) {
      const u64* hp = hbuf + ((size_t)((grp*2 + pr)*2 + dir))*2048 + cb_b*128 + cb_k;
      int spin = 0;
      for (;;) {
        u64 bad = 0;
#pragma unroll
        for (int j=0;j<8;++j) bad |= (cu[j] ^ tgr);
        if (__all((bad & 1) == 0)) break;
        if (++spin > (1<<16)) break;   // fail loud, never hang
#pragma unroll
        for (int j=0;j<8;++j)
          cu[j] = __hip_atomic_load(hp + j*16, __ATOMIC_RELAXED, __HIP_MEMORY_SCOPE_AGENT);
        __builtin_amdgcn_s_sleep(1);
      }
      // stage to LDS (coalesced-strided: lanes stride 8B -> ~no bank conflicts)
      u64* hz = &hstage[pr][cb_b*129 + cb_k];
#pragma unroll
      for (int j=0;j<8;++j) hz[j*16] = cu[j];
      barrier_lgkm();

      const u64* hs = &hstage[pr][cc*129];
#pragma unroll
      for (int kk=0;kk<16;++kk) {
        u64 alo = hs[kk*8 + q];
        u64 ahi = hs[kk*8 + q + 4];
        f16x4v l4 = __builtin_bit_cast(f16x4v, alo);
        f16x4v h4 = __builtin_bit_cast(f16x4v, ahi);
        f16x8 af; af[0]=l4[0];af[1]=l4[1];af[2]=l4[2];af[3]=l4[3];
        af[4]=h4[0];af[5]=h4[1];af[6]=h4[2];af[7]=h4[3];
#pragma unroll
        for (int g=0;g<4;++g)
          acc[g] = __builtin_amdgcn_mfma_f32_16x16x32_f16(af, Wf[kk][g], acc[g], 0,0,0);
      }
    }

    // activations — fully register-local (all 4 gates in this lane)
    f16x8 c01 = __builtin_bit_cast(f16x8, gxa);   // gates 0,1 x rr
    f16x8 c23 = __builtin_bit_cast(f16x8, gxb);   // gates 2,3 x rr
    float hnv[4];
#pragma unroll
    for (int rr=0;rr<4;++rr) {
      float gi = acc[0][rr] + (float)c01[rr];
      float gj = acc[1][rr] + (float)c01[4+rr];
      float gf = acc[2][rr] + (float)c23[rr];
      float go = acc[3][rr] + (float)c23[4+rr];
      float hv = hst[rr];
      if (s < Lr[rr]) {
        float cn = sigf(gf + 1.0f)*cst[rr] + sigf(gi)*tanh_f(gj);
        float hn = sigf(go)*tanh_f(cn);
        cst[rr] = cn; hst[rr] = hn; hv = hn;
      }
      hnv[rr] = hv;
    }

    // ---- VMEM issue order: publish -> prefetch -> (sched fence) -> out ----
    // 1) tagged publish: earliest possible visibility at the MALL
    size_t wb = ((size_t)((grp*2 + ((s+1)&1))*2 + dir))*2048;
#pragma unroll
    for (int rr=0;rr<4;++rr) {
      f16 hf = (f16)hnv[rr];
      u32 v = (u32)__builtin_bit_cast(unsigned short, hf);
      if ((cc & 3) == 0) v = (v & 0xFFFEu) | (u32)tgw;
      u32 pk = v | (((u32)__shfl_down((int)v, 1)) << 16);
      u32 pk2 = (u32)__shfl_down((int)pk, 2);
      if ((cc & 3) == 0) {
        u64 val = (u64)pk | ((u64)pk2 << 32);
        int b = q*4 + rr;
        __hip_atomic_store(hbuf + wb + b*128 + rank*16 + ct*4 + (cc>>2), val,
                           __ATOMIC_RELAXED, __HIP_MEMORY_SCOPE_AGENT);
      }
    }

    // 2) prefetch candidates + gx for s+1 (checked next iteration); these are
    //    the loads next step waits on — keep them OLDER than the out stores.
    if (s + 1 < NT) {
      const u64* hpn = hbuf + wb + cb_b*128 + cb_k;
#pragma unroll
      for (int j=0;j<8;++j)
        cu[j] = __hip_atomic_load(hpn + j*16, __ATOMIC_RELAXED, __HIP_MEMORY_SCOPE_AGENT);
      const f16* gp = gxp + (size_t)(dir*NT + (s+1))*65536
                      + ((size_t)(rank*2 + grp)*256 + tid)*16;
      gxa = *(const uint4*)gp;
      gxb = *(const uint4*)(gp + 8);
    }

    // 3) out stores LAST (non-temporal; never drained inside the loop)
    __builtin_amdgcn_sched_barrier(0);
#pragma unroll
    for (int rr=0;rr<4;++rr) {
      if (s < Lr[rr]) {
        int b = grp*16 + q*4 + rr;
        int u = dir ? (Lr[rr]-1-s) : s;
        __builtin_nontemporal_store(hnv[rr],
            &out[((size_t)b*NT + u)*(2*NH) + (size_t)dir*NH + ncol0 + cc]);
      }
    }
  }
}

extern "C" void kernel_launch(void* const* d_in, const int* in_sizes, int n_in,
                              void* d_out, int out_size, void* d_ws, size_t ws_size,
                              hipStream_t stream) {
  (void)in_sizes; (void)n_in; (void)out_size; (void)ws_size;
  const float* x      = (const float*)d_in[0];
  const int*   seqlen = (const int*)  d_in[1];
  const float* Wfw    = (const float*)d_in[2];
  const float* bfw    = (const float*)d_in[3];
  const float* Wbw    = (const float*)d_in[4];
  const float* bbw    = (const float*)d_in[5];
  float* out = (float*)d_out;
  unsigned char* ws = (unsigned char*)d_ws;

  f16* xh   = (f16*)(ws + XH_OFF);
  f16* Wt   = (f16*)(ws + WT_OFF);
  f16* gxp  = (f16*)(ws + GX_OFF);
  u64* hbuf = (u64*)(ws + HB_OFF);

  size_t no = (size_t)NB*NT*2*NH/4;            // float4 count of d_out
  size_t nz = HB_BYTES/16;                     // uint4 count of hbuf
  k_zero<<<dim3(2048), dim3(256), 0, stream>>>((float4*)d_out, no,
                                               (uint4*)(ws + HB_OFF), nz);
  k_cvt<<<dim3((NB*NT*NF/4)/256), dim3(256), 0, stream>>>(x, xh);
  k_tw <<<dim3(4096), dim3(256), 0, stream>>>(Wfw, Wbw, Wt);
  k_gx <<<dim3(128, 16, 2), dim3(256), 0, stream>>>(xh, Wt, bfw, bbw, seqlen, gxp);
  k_rnn<<<dim3(32), dim3(256), 0, stream>>>(gxp, Wt, hbuf, seqlen, out);
}

// Round 13
// 2351.705 us; speedup vs baseline: 1.0377x; 1.0377x over previous
//
#include <hip/hip_runtime.h>

typedef _Float16 f16;
typedef _Float16 f16x4v __attribute__((ext_vector_type(4)));
typedef _Float16 f16x8  __attribute__((ext_vector_type(8)));
typedef float    f32x4  __attribute__((ext_vector_type(4)));
typedef unsigned long long u64;
typedef unsigned int u32;

#define NB 32
#define NT 512
#define NF 512
#define NH 512
#define NG 2048   // 4*NH gate columns

// workspace layout (bytes)
static const size_t XH_OFF   = 0;
static const size_t XH_BYTES = (size_t)NB*NT*NF*2;        // 16 MiB fp16 x
static const size_t WT_OFF   = XH_OFF + XH_BYTES;
static const size_t WT_BYTES = (size_t)2*NG*1024*2;       //  8 MiB Wt[dir][col][k] fp16
static const size_t GX_OFF   = WT_OFF + WT_BYTES;
static const size_t GX_BYTES = (size_t)2*NT*65536*2;      // 128 MiB gxp[dir*NT+slot][rank][grp][thr256][16]
static const size_t HB_OFF   = GX_OFF + GX_BYTES;
static const size_t HB_BYTES = (size_t)2*2*2*16*128*8;    // 128 KiB hbuf[grp][par][dir][b16][ko128] u64

__device__ __forceinline__ float sigf(float x){ return 1.0f/(1.0f+__expf(-x)); }
__device__ __forceinline__ float tanh_f(float x){ return 1.0f - 2.0f/(__expf(2.0f*x)+1.0f); }

// raw barrier: LDS-ordering only; VMEM (stores/prefetches) stay in flight.
__device__ __forceinline__ void barrier_lgkm() {
  asm volatile("s_waitcnt lgkmcnt(0)" ::: "memory");
  __builtin_amdgcn_sched_barrier(0);
  __builtin_amdgcn_s_barrier();
  __builtin_amdgcn_sched_barrier(0);
  asm volatile("" ::: "memory");
}

__global__ void k_zero(float4* o, size_t no, uint4* z, size_t nz) {
  size_t i = (size_t)blockIdx.x*blockDim.x + threadIdx.x;
  size_t st = (size_t)gridDim.x*blockDim.x;
  float4 fz = make_float4(0.f,0.f,0.f,0.f);
  uint4  uz = make_uint4(0u,0u,0u,0u);
  for (size_t j=i; j<no; j+=st) o[j]=fz;
  for (size_t j=i; j<nz; j+=st) z[j]=uz;
}

__global__ void k_cvt(const float* __restrict__ x, f16* __restrict__ xh) {
  size_t i = ((size_t)blockIdx.x*blockDim.x + threadIdx.x)*4;
  float4 v = *(const float4*)(x+i);
  f16x4v h; h[0]=(f16)v.x; h[1]=(f16)v.y; h[2]=(f16)v.z; h[3]=(f16)v.w;
  *(f16x4v*)(xh+i) = h;
}

// W [1024][2048] f32 -> Wt[dir][col 2048][k 1024] fp16 (tiled transpose)
__global__ void k_tw(const float* __restrict__ Wfw, const float* __restrict__ Wbw,
                     f16* __restrict__ Wt) {
  __shared__ f16 tile[32][33];
  int b = blockIdx.x;
  int dir = b >> 11; int rem = b & 2047;
  int kt = rem >> 6, ct = rem & 63;
  const float* W = dir ? Wbw : Wfw;
  int tx = threadIdx.x & 31, ty0 = threadIdx.x >> 5;
  int k0 = kt*32, c0 = ct*32;
  for (int yy=ty0; yy<32; yy+=8)
    tile[yy][tx] = (f16)W[(size_t)(k0+yy)*2048 + c0 + tx];
  __syncthreads();
  f16* Wd = Wt + (size_t)dir*2048*1024;
  for (int yy=ty0; yy<32; yy+=8)
    Wd[(size_t)(c0+yy)*1024 + k0 + tx] = tile[tx][yy];
}

// gxp = x@Wx + bias, consumer layout:
// [dir*NT+slot][rank8][grp2][thread256 = ct*64+q*16+cc][gate4][rr4] f16
// bw time reversal folded into slot (bijection per batch).
__global__ __launch_bounds__(256) void k_gx(const f16* __restrict__ xh,
    const f16* __restrict__ Wt, const float* __restrict__ bfw,
    const float* __restrict__ bbw, const int* __restrict__ seqlen,
    f16* __restrict__ gxp)
{
  __shared__ f16 As[128*32];
  __shared__ f16 Bs[128*32];
  int bm0 = blockIdx.x * 128;
  int bn0 = blockIdx.y * 128;
  int dir = blockIdx.z;
  const f16* Wd = Wt + (size_t)dir*NG*1024;
  const float* bias = dir ? bbw : bfw;

  int tid = threadIdx.x;
  int w = tid>>6, lane = tid&63;
  int cc = lane&15, q = lane>>4;
  int wm = w>>1, wn = w&1;

  f32x4 acc[4][4];
#pragma unroll
  for (int i=0;i<4;++i)
#pragma unroll
    for (int j=0;j<4;++j) acc[i][j] = (f32x4){0.f,0.f,0.f,0.f};

  for (int kt=0; kt<16; ++kt) {
    int k0 = kt*32;
#pragma unroll
    for (int c=0;c<2;++c) {
      int ch = w*2 + c;
      int row = ch*16 + (lane>>2);
      int cph = (lane&3)*16;
      int clg = cph ^ (((row>>1)&3)<<4);
      const f16* ga = xh + (size_t)(bm0+row)*NF   + k0 + (clg>>1);
      const f16* gb = Wd + (size_t)(bn0+row)*1024 + k0 + (clg>>1);
      __builtin_amdgcn_global_load_lds(
          (const __attribute__((address_space(1))) u32*)ga,
          (__attribute__((address_space(3))) u32*)(As + ch*512), 16, 0, 0);
      __builtin_amdgcn_global_load_lds(
          (const __attribute__((address_space(1))) u32*)gb,
          (__attribute__((address_space(3))) u32*)(Bs + ch*512), 16, 0, 0);
    }
    __syncthreads();

    f16x8 av[4], bv[4];
#pragma unroll
    for (int mi=0;mi<4;++mi) {
      int r = wm*64 + mi*16 + cc;
      int sw = ((r>>1)&3)<<4;
      u64 lo = *(const u64*)&As[r*32 + ((((q*8)   ) ^ sw)>>1)];
      u64 hi = *(const u64*)&As[r*32 + ((((q*8)+32) ^ sw)>>1)];
      f16x4v l4 = __builtin_bit_cast(f16x4v, lo);
      f16x4v h4 = __builtin_bit_cast(f16x4v, hi);
      f16x8 a; a[0]=l4[0];a[1]=l4[1];a[2]=l4[2];a[3]=l4[3];
      a[4]=h4[0];a[5]=h4[1];a[6]=h4[2];a[7]=h4[3];
      av[mi]=a;
    }
#pragma unroll
    for (int ni=0;ni<4;++ni) {
      int r = wn*64 + ni*16 + cc;
      int sw = ((r>>1)&3)<<4;
      u64 lo = *(const u64*)&Bs[r*32 + ((((q*8)   ) ^ sw)>>1)];
      u64 hi = *(const u64*)&Bs[r*32 + ((((q*8)+32) ^ sw)>>1)];
      f16x4v l4 = __builtin_bit_cast(f16x4v, lo);
      f16x4v h4 = __builtin_bit_cast(f16x4v, hi);
      f16x8 a; a[0]=l4[0];a[1]=l4[1];a[2]=l4[2];a[3]=l4[3];
      a[4]=h4[0];a[5]=h4[1];a[6]=h4[2];a[7]=h4[3];
      bv[ni]=a;
    }
#pragma unroll
    for (int mi=0;mi<4;++mi)
#pragma unroll
      for (int ni=0;ni<4;++ni)
        acc[mi][ni] = __builtin_amdgcn_mfma_f32_16x16x32_f16(av[mi], bv[ni], acc[mi][ni], 0,0,0);
    __syncthreads();
  }

  // epilogue: scatter into consumer layout
  int b = bm0 >> 9;             // this block's single batch
  int L = seqlen[b];
  int grp = b >> 4, bl = b & 15;
  int q_c = bl >> 2, rr_c = bl & 3;
#pragma unroll
  for (int ni=0;ni<4;++ni) {
    int col = bn0 + wn*64 + ni*16 + cc;
    int gate = col >> 9, n = col & 511;
    int rk = n >> 6, c_l = n & 63;
    int ct_c = c_l >> 4, cc_c = c_l & 15;
    float bvl = bias[col];
    size_t coff = (size_t)((((rk*2 + grp)*256 + ct_c*64 + q_c*16 + cc_c))*16 + gate*4 + rr_c);
#pragma unroll
    for (int mi=0;mi<4;++mi)
#pragma unroll
      for (int rr=0;rr<4;++rr) {
        int t = (bm0&511) + wm*64 + mi*16 + q*4 + rr;
        int slot = dir ? ((t < L) ? (L-1-t) : t) : t;
        gxp[(size_t)(dir*NT + slot)*65536 + coff] = (f16)(acc[mi][ni][rr] + bvl);
      }
  }
}

// Persistent recurrence: 32 blocks (dir x rank x grp), 256 threads (4 waves).
// Wave ct owns cols [rank*64 + ct*16, +16) x ALL 4 gates -> all 4 gates of one
// (b,c) live in the SAME lane's accumulators: act is register-local. One
// barrier/step (double-buffered hstage). Wf = 256 VGPRs pinned resident.
// Tag-in-data ping-pong (proven): tag=((s+1)>>1)&1 in LSB of each u64;
// candidates prefetched at end of step s, checked at step s+1.
// R11 ordering restored (best measured): act -> out -> publish -> prefetch.
__global__ __launch_bounds__(256, 1)
void k_rnn(const f16* __restrict__ gxp, const f16* __restrict__ Wt,
           u64* hbuf, const int* __restrict__ seqlen, float* __restrict__ out)
{
  __shared__ u64 hstage[2][16*129];
  int bid = blockIdx.x;
  int dir = bid >> 4, rank = (bid >> 1) & 7, grp = bid & 1;
  int tid = threadIdx.x;
  int ct = tid >> 6, lane = tid & 63, cc = lane & 15, q = lane >> 4;
  int ncol0 = rank*64 + ct*16;

  // Persistent W_h: col = g*NH + ncol0 + cc; k = 512 + kk*32 + q*4 (+16)
  f16x8 Wf[16][4];
  {
    const f16* Wd = Wt + (size_t)dir*NG*1024;
#pragma unroll
    for (int kk=0;kk<16;++kk)
#pragma unroll
      for (int g=0;g<4;++g) {
        const f16* pp = Wd + (size_t)(g*NH + ncol0 + cc)*1024 + 512 + kk*32 + q*4;
        f16x4v lo = *(const f16x4v*)pp;
        f16x4v hi = *(const f16x4v*)(pp+16);
        f16x8 a; a[0]=lo[0];a[1]=lo[1];a[2]=lo[2];a[3]=lo[3];
        a[4]=hi[0];a[5]=hi[1];a[6]=hi[2];a[7]=hi[3];
        Wf[kk][g] = a;
      }
  }
  // pin: values become asm-opaque -> cannot be rematerialized (re-loaded) in-loop
#pragma unroll
  for (int kk=0;kk<16;++kk)
#pragma unroll
    for (int g=0;g<4;++g)
      asm volatile("" : "+v"(Wf[kk][g]));

  int Lr[4];
#pragma unroll
  for (int rr=0;rr<4;++rr) Lr[rr] = seqlen[grp*16 + q*4 + rr];

  float cst[4] = {0.f,0.f,0.f,0.f}, hst[4] = {0.f,0.f,0.f,0.f};

  int cb_b = tid >> 4;      // candidate batch 0..15
  int cb_k = tid & 15;      // candidate ko base
  u64 cu[8] = {0,0,0,0,0,0,0,0};

  uint4 gxa = *(const uint4*)(gxp + (size_t)(dir*NT + 0)*65536
                              + ((size_t)(rank*2 + grp)*256 + tid)*16);
  uint4 gxb = *(const uint4*)(gxp + (size_t)(dir*NT + 0)*65536
                              + ((size_t)(rank*2 + grp)*256 + tid)*16 + 8);

  for (int s = 0; s < NT; ++s) {
    int pr = s & 1;
    u64 tgr = (u64)(((s+1)>>1) & 1);
    u64 tgw = (u64)(((s+2)>>1) & 1);

    f32x4 acc[4];
#pragma unroll
    for (int g=0;g<4;++g) acc[g] = (f32x4){0.f,0.f,0.f,0.f};

    if (s > 0) {
      const u64* hp = hbuf + ((size_t)((grp*2 + pr)*2 + dir))*2048 + cb_b*128 + cb_k;
      int spin = 0;
      for (;;) {
        u64 bad = 0;
#pragma unroll
        for (int j=0;j<8;++j) bad |= (cu[j] ^ tgr);
        if (__all((bad & 1) == 0)) break;
        if (++spin > (1<<16)) break;   // fail loud, never hang
#pragma unroll
        for (int j=0;j<8;++j)
          cu[j] = __hip_atomic_load(hp + j*16, __ATOMIC_RELAXED, __HIP_MEMORY_SCOPE_AGENT);
        __builtin_amdgcn_s_sleep(1);
      }
      // stage to LDS (coalesced-strided: lanes stride 8B -> ~no bank conflicts)
      u64* hz = &hstage[pr][cb_b*129 + cb_k];
#pragma unroll
      for (int j=0;j<8;++j) hz[j*16] = cu[j];
      barrier_lgkm();

      const u64* hs = &hstage[pr][cc*129];
#pragma unroll
      for (int kk=0;kk<16;++kk) {
        u64 alo = hs[kk*8 + q];
        u64 ahi = hs[kk*8 + q + 4];
        f16x4v l4 = __builtin_bit_cast(f16x4v, alo);
        f16x4v h4 = __builtin_bit_cast(f16x4v, ahi);
        f16x8 af; af[0]=l4[0];af[1]=l4[1];af[2]=l4[2];af[3]=l4[3];
        af[4]=h4[0];af[5]=h4[1];af[6]=h4[2];af[7]=h4[3];
#pragma unroll
        for (int g=0;g<4;++g)
          acc[g] = __builtin_amdgcn_mfma_f32_16x16x32_f16(af, Wf[kk][g], acc[g], 0,0,0);
      }
    }

    // activations — fully register-local (all 4 gates in this lane)
    f16x8 c01 = __builtin_bit_cast(f16x8, gxa);   // gates 0,1 x rr
    f16x8 c23 = __builtin_bit_cast(f16x8, gxb);   // gates 2,3 x rr
    float hnv[4];
#pragma unroll
    for (int rr=0;rr<4;++rr) {
      float gi = acc[0][rr] + (float)c01[rr];
      float gj = acc[1][rr] + (float)c01[4+rr];
      float gf = acc[2][rr] + (float)c23[rr];
      float go = acc[3][rr] + (float)c23[4+rr];
      float hv = hst[rr];
      if (s < Lr[rr]) {
        float cn = sigf(gf + 1.0f)*cst[rr] + sigf(gi)*tanh_f(gj);
        float hn = sigf(go)*tanh_f(cn);
        cst[rr] = cn; hst[rr] = hn; hv = hn;
      }
      hnv[rr] = hv;
    }

    // out stores — fire and forget (R11 best-measured order)
#pragma unroll
    for (int rr=0;rr<4;++rr) {
      if (s < Lr[rr]) {
        int b = grp*16 + q*4 + rr;
        int u = dir ? (Lr[rr]-1-s) : s;
        out[((size_t)b*NT + u)*(2*NH) + (size_t)dir*NH + ncol0 + cc] = hnv[rr];
      }
    }

    // tagged publish: 2x shfl_down packs 4 cols/u64, (cc&3)==0 lanes store
    size_t wb = ((size_t)((grp*2 + ((s+1)&1))*2 + dir))*2048;
#pragma unroll
    for (int rr=0;rr<4;++rr) {
      f16 hf = (f16)hnv[rr];
      u32 v = (u32)__builtin_bit_cast(unsigned short, hf);
      if ((cc & 3) == 0) v = (v & 0xFFFEu) | (u32)tgw;
      u32 pk = v | (((u32)__shfl_down((int)v, 1)) << 16);
      u32 pk2 = (u32)__shfl_down((int)pk, 2);
      if ((cc & 3) == 0) {
        u64 val = (u64)pk | ((u64)pk2 << 32);
        int b = q*4 + rr;
        __hip_atomic_store(hbuf + wb + b*128 + rank*16 + ct*4 + (cc>>2), val,
                           __ATOMIC_RELAXED, __HIP_MEMORY_SCOPE_AGENT);
      }
    }

    // prefetch candidates + gx for s+1 (checked next iteration)
    if (s + 1 < NT) {
      const u64* hpn = hbuf + wb + cb_b*128 + cb_k;
#pragma unroll
      for (int j=0;j<8;++j)
        cu[j] = __hip_atomic_load(hpn + j*16, __ATOMIC_RELAXED, __HIP_MEMORY_SCOPE_AGENT);
      const f16* gp = gxp + (size_t)(dir*NT + (s+1))*65536
                      + ((size_t)(rank*2 + grp)*256 + tid)*16;
      gxa = *(const uint4*)gp;
      gxb = *(const uint4*)(gp + 8);
    }
  }
}

extern "C" void kernel_launch(void* const* d_in, const int* in_sizes, int n_in,
                              void* d_out, int out_size, void* d_ws, size_t ws_size,
                              hipStream_t stream) {
  (void)in_sizes; (void)n_in; (void)out_size; (void)ws_size;
  const float* x      = (const float*)d_in[0];
  const int*   seqlen = (const int*)  d_in[1];
  const float* Wfw    = (const float*)d_in[2];
  const float* bfw    = (const float*)d_in[3];
  const float* Wbw    = (const float*)d_in[4];
  const float* bbw    = (const float*)d_in[5];
  float* out = (float*)d_out;
  unsigned char* ws = (unsigned char*)d_ws;

  f16* xh   = (f16*)(ws + XH_OFF);
  f16* Wt   = (f16*)(ws + WT_OFF);
  f16* gxp  = (f16*)(ws + GX_OFF);
  u64* hbuf = (u64*)(ws + HB_OFF);

  size_t no = (size_t)NB*NT*2*NH/4;            // float4 count of d_out
  size_t nz = HB_BYTES/16;                     // uint4 count of hbuf
  k_zero<<<dim3(2048), dim3(256), 0, stream>>>((float4*)d_out, no,
                                               (uint4*)(ws + HB_OFF), nz);
  k_cvt<<<dim3((NB*NT*NF/4)/256), dim3(256), 0, stream>>>(x, xh);
  k_tw <<<dim3(4096), dim3(256), 0, stream>>>(Wfw, Wbw, Wt);
  k_gx <<<dim3(128, 16, 2), dim3(256), 0, stream>>>(xh, Wt, bfw, bbw, seqlen, gxp);
  k_rnn<<<dim3(32), dim3(256), 0, stream>>>(gxp, Wt, hbuf, seqlen, out);
}